// Round 4
// baseline (1069.664 us; speedup 1.0000x reference)
//
#include <hip/hip_runtime.h>
#include <math.h>

// Problem constants
#define BATCH 32
#define TLEN  4096
#define DDIM  512
#define BM    64      // rows per tile
#define BLOCK 512     // 8 waves; wave w owns output cols [64w, 64w+64)
#define NT    8       // tiles per persistent block; grid = 2048/NT = 256 = 1/CU
// r10: persistent blocks + async-STAGE split (T14). r9 fixed W gathers
// (400->278us) but HBM duty is 12.5%: the h stage phase runs serial between
// barriers with 1 resident block/CU, exposing full HBM burst+latency per tile.
// Now each block owns 8 consecutive tiles; next tile's h is loaded into 16
// float4 regs right after GEMM1 (issue-early), converted+written to LDS after
// GEMM2's u-reads complete (write-late). Stage serial cost/tile drops to the
// convert+ds_write tail. Reg budget ~190 < 256 cap at 2 waves/SIMD: no spill
// (r8's failure was the forced VGPR=40; here the allocator is unconstrained).

typedef __attribute__((ext_vector_type(8)))  short bf16x8;   // MFMA A/B frag
typedef __attribute__((ext_vector_type(16))) float f32x16;   // MFMA C/D frag (32x32)
typedef __attribute__((ext_vector_type(4)))  short s16x4;    // 8B LDS store

__device__ __forceinline__ short f32_to_bf16_rne(float f) {
    union { float f; unsigned int u; } v; v.f = f;
    unsigned int r = (v.u + 0x7FFFu + ((v.u >> 16) & 1u)) >> 16;
    return (short)r;
}
__device__ __forceinline__ float fast_tanh(float x) {
    x = fminf(fmaxf(x, -15.f), 15.f);
    float t = __expf(2.0f * x);
    return (t - 1.0f) / (t + 1.0f);
}

// XOR swizzle on 16B (8-short) granules. Measured 0 bank conflicts (r2-r6).
__device__ __forceinline__ int lds_idx(int r, int c) {
    int g = (c >> 3) ^ (r & 31);
    return r * DDIM + (g << 3) + (c & 7);
}

// --- kernel 1: W fp32 -> bf16 packed into MFMA-fragment order; zero l/g ------
// Element (e, d): E=e>>5, r=e&31, C=d>>4, half=(d>>3)&1, j=d&7
//   packed[ ((E*32 + C)*64 + half*32 + r)*8 + j ]
// Kernel-side (lane l): tile (E,C) base + l*8 supplies
//   W[E*32 + (l&31)][C*16 + 8*(l>>5) + j]  == MFMA fragment element.
__global__ void prep_kernel(const float* __restrict__ W1, const float* __restrict__ W2,
                            short* __restrict__ W1pk, short* __restrict__ W2pk,
                            float* __restrict__ lbuf, float* __restrict__ gbuf) {
    int i = blockIdx.x * blockDim.x + threadIdx.x;   // 0 .. 32767
    int e  = i >> 6;                 // source row
    int d0 = (i & 63) << 3;          // source col of this 8-run
    int E = e >> 5, r = e & 31, C = d0 >> 4, half = (d0 >> 3) & 1;
    size_t src = (size_t)e * DDIM + d0;
    size_t dst = ((size_t)(E * 32 + C) * 64 + half * 32 + r) * 8;
    bf16x8 p1, p2;
    #pragma unroll
    for (int j = 0; j < 8; ++j) {
        p1[j] = f32_to_bf16_rne(W1[src + j]);
        p2[j] = f32_to_bf16_rne(W2[src + j]);
    }
    *(bf16x8*)&W1pk[dst] = p1;
    *(bf16x8*)&W2pk[dst] = p2;
    if (i < BATCH * DDIM) { lbuf[i] = 0.f; gbuf[i] = 0.f; }
}

// --- kernel 2: persistent fused u=tanh(hW1^T+b1); s=uW2^T; accumulate l,g ----
__global__ __launch_bounds__(BLOCK, 2)
void main_kernel(const float* __restrict__ h,
                 const short* __restrict__ W1pk,
                 const float* __restrict__ b1,
                 const short* __restrict__ W2pk,
                 float* __restrict__ lbuf, float* __restrict__ gbuf) {
    __shared__ __align__(16) short sh[BM * DDIM];   // 64 KB: h tile, then u tile

    const int tid  = threadIdx.x;
    const int wave = tid >> 6;
    const int lane = tid & 63;
    const int l32  = lane & 31;
    const int h5   = lane >> 5;       // 0/1
    const int e0   = wave * 64;       // this wave's 64-col slice (both GEMMs)
    const int tile0 = blockIdx.x * NT;
    const int b     = (tile0 * BM) / TLEN;   // 8 tiles = 512 rows, 8 | 4096: const

    const short* W1p = W1pk + (size_t)(e0 >> 5) * (32 * 512) + lane * 8;
    const short* W2p = W2pk + (size_t)(e0 >> 5) * (32 * 512) + lane * 8;

    // ---- prologue: stage tile 0 (load, convert, LDS write) ----
    {
        const float4* hp = (const float4*)(h + (size_t)tile0 * BM * DDIM);
        #pragma unroll
        for (int i = 0; i < 16; ++i) {
            int idx  = tid + i * BLOCK;
            float4 v = hp[idx];
            int flat = idx * 4;
            int r = flat >> 9;                   // /512
            int c = flat & (DDIM - 1);
            s16x4 p;
            p.x = f32_to_bf16_rne(v.x); p.y = f32_to_bf16_rne(v.y);
            p.z = f32_to_bf16_rne(v.z); p.w = f32_to_bf16_rne(v.w);
            *(s16x4*)&sh[lds_idx(r, c)] = p;
        }
    }

    for (int t = 0; t < NT; ++t) {
        const int row0 = (tile0 + t) * BM;
        __syncthreads();                 // barrier A: staged h(t) visible

        // ====== GEMM1 (swapped): C[e][t] = sum_d W1[e][d] * h[t][d] ======
        f32x16 acc[2][2];                 // [eb][tb]
        #pragma unroll
        for (int i = 0; i < 2; ++i)
            #pragma unroll
            for (int j = 0; j < 2; ++j)
                #pragma unroll
                for (int r = 0; r < 16; ++r) acc[i][j][r] = 0.f;

        bf16x8 wc[2][2], wn[2][2];        // [eb][ksub], 1-iter prefetch
        #pragma unroll
        for (int eb = 0; eb < 2; ++eb)
            #pragma unroll
            for (int ks = 0; ks < 2; ++ks)
                wc[eb][ks] = *(const bf16x8*)(W1p + (eb * 32 + ks) * 512);

        for (int k0 = 0; k0 < DDIM; k0 += 32) {
            const int kb = k0 >> 4;
            bf16x8 hf[2][2];              // [tb][ksub]
            #pragma unroll
            for (int tb = 0; tb < 2; ++tb)
                #pragma unroll
                for (int ks = 0; ks < 2; ++ks)
                    hf[tb][ks] = *(const bf16x8*)&sh[lds_idx(tb * 32 + l32,
                                                             k0 + ks * 16 + 8 * h5)];
            // prefetch next k-chunk (last iter overreads into adjacent ws: ok)
            #pragma unroll
            for (int eb = 0; eb < 2; ++eb)
                #pragma unroll
                for (int ks = 0; ks < 2; ++ks)
                    wn[eb][ks] = *(const bf16x8*)(W1p + (eb * 32 + kb + 2 + ks) * 512);
            #pragma unroll
            for (int eb = 0; eb < 2; ++eb)
                #pragma unroll
                for (int tb = 0; tb < 2; ++tb)
                    #pragma unroll
                    for (int ks = 0; ks < 2; ++ks)
                        acc[eb][tb] = __builtin_amdgcn_mfma_f32_32x32x16_bf16(
                            wc[eb][ks], hf[tb][ks], acc[eb][tb], 0, 0, 0);
            #pragma unroll
            for (int eb = 0; eb < 2; ++eb)
                #pragma unroll
                for (int ks = 0; ks < 2; ++ks) wc[eb][ks] = wn[eb][ks];
        }

        // issue GEMM2's first W2 frags: L2 latency hides under tanh+write+bars
        bf16x8 w2c[2][2], w2n[2][2];      // [cb][ksub]
        #pragma unroll
        for (int cb = 0; cb < 2; ++cb)
            #pragma unroll
            for (int ks = 0; ks < 2; ++ks)
                w2c[cb][ks] = *(const bf16x8*)(W2p + (cb * 32 + ks) * 512);

        // bias + tanh. C/D: col(t)=lane&31, row(e)=(r&3)+8*(r>>2)+4*h5 (+32*eb)
        #pragma unroll
        for (int eb = 0; eb < 2; ++eb) {
            float4 bv[4];
            #pragma unroll
            for (int q = 0; q < 4; ++q)
                bv[q] = *(const float4*)&b1[e0 + 32 * eb + 4 * h5 + 8 * q];
            #pragma unroll
            for (int tb = 0; tb < 2; ++tb)
                #pragma unroll
                for (int r = 0; r < 16; ++r)
                    acc[eb][tb][r] = fast_tanh(acc[eb][tb][r] + bv[r >> 2][r & 3]);
        }

        __syncthreads();                 // barrier B: h(t) reads done

        // T14 issue-early: next tile's h -> 16 float4 regs (uniform guard)
        float4 stg[16];
        const bool pf = (t + 1 < NT);
        if (pf) {
            const float4* hpn = (const float4*)(h + (size_t)(row0 + BM) * DDIM);
            #pragma unroll
            for (int i = 0; i < 16; ++i) stg[i] = hpn[tid + i * BLOCK];
        }

        // write u^T frags as u[t][e]: lane owns fixed t, 4-consec-e runs -> b64
        #pragma unroll
        for (int eb = 0; eb < 2; ++eb)
            #pragma unroll
            for (int tb = 0; tb < 2; ++tb) {
                int tt = tb * 32 + l32;
                #pragma unroll
                for (int q = 0; q < 4; ++q) {
                    int e = e0 + 32 * eb + 4 * h5 + 8 * q;
                    s16x4 p;
                    p.x = f32_to_bf16_rne(acc[eb][tb][4 * q + 0]);
                    p.y = f32_to_bf16_rne(acc[eb][tb][4 * q + 1]);
                    p.z = f32_to_bf16_rne(acc[eb][tb][4 * q + 2]);
                    p.w = f32_to_bf16_rne(acc[eb][tb][4 * q + 3]);
                    *(s16x4*)&sh[lds_idx(tt, e)] = p;
                }
            }
        __syncthreads();                 // barrier C: u visible

        // ====== GEMM2 (normal): s[t][e2] = sum_e u[t][e] * W2[e2][e] ======
        f32x16 acc2[2][2];                // [tb][cb]
        #pragma unroll
        for (int i = 0; i < 2; ++i)
            #pragma unroll
            for (int j = 0; j < 2; ++j)
                #pragma unroll
                for (int r = 0; r < 16; ++r) acc2[i][j][r] = 0.f;

        for (int k0 = 0; k0 < DDIM; k0 += 32) {
            const int kb = k0 >> 4;
            bf16x8 uf[2][2];              // [tb][ksub]
            #pragma unroll
            for (int tb = 0; tb < 2; ++tb)
                #pragma unroll
                for (int ks = 0; ks < 2; ++ks)
                    uf[tb][ks] = *(const bf16x8*)&sh[lds_idx(tb * 32 + l32,
                                                             k0 + ks * 16 + 8 * h5)];
            #pragma unroll
            for (int cb = 0; cb < 2; ++cb)
                #pragma unroll
                for (int ks = 0; ks < 2; ++ks)
                    w2n[cb][ks] = *(const bf16x8*)(W2p + (cb * 32 + kb + 2 + ks) * 512);
            #pragma unroll
            for (int tb = 0; tb < 2; ++tb)
                #pragma unroll
                for (int cb = 0; cb < 2; ++cb)
                    #pragma unroll
                    for (int ks = 0; ks < 2; ++ks)
                        acc2[tb][cb] = __builtin_amdgcn_mfma_f32_32x32x16_bf16(
                            uf[tb][ks], w2c[cb][ks], acc2[tb][cb], 0, 0, 0);
            #pragma unroll
            for (int cb = 0; cb < 2; ++cb)
                #pragma unroll
                for (int ks = 0; ks < 2; ++ks) w2c[cb][ks] = w2n[cb][ks];
        }

        __syncthreads();                 // barrier D: u reads done

        // T14 write-late: convert staged regs, overwrite sh with h(t+1)
        if (pf) {
            #pragma unroll
            for (int i = 0; i < 16; ++i) {
                int idx  = tid + i * BLOCK;
                int flat = idx * 4;
                int r = flat >> 9;
                int c = flat & (DDIM - 1);
                s16x4 p;
                p.x = f32_to_bf16_rne(stg[i].x); p.y = f32_to_bf16_rne(stg[i].y);
                p.z = f32_to_bf16_rne(stg[i].z); p.w = f32_to_bf16_rne(stg[i].w);
                *(s16x4*)&sh[lds_idx(r, c)] = p;
            }
        }

        // epilogue: e = exp(s); l += e; g += e*h (h re-read, L2-resident)
        #pragma unroll
        for (int cb = 0; cb < 2; ++cb) {
            const int e2 = e0 + 32 * cb + l32;
            const float* hp2 = h + (size_t)row0 * DDIM + e2;
            float lsum = 0.f, gsum = 0.f;
            #pragma unroll
            for (int tb = 0; tb < 2; ++tb)
                #pragma unroll
                for (int r = 0; r < 16; ++r) {
                    int tt = tb * 32 + 4 * h5 + (r & 3) + 8 * (r >> 2);
                    float ev = __expf(acc2[tb][cb][r]);   // |s| small: no max-sub
                    lsum += ev;
                    gsum += ev * hp2[(size_t)tt * DDIM];
                }
            lsum += __shfl_xor(lsum, 32);
            gsum += __shfl_xor(gsum, 32);
            if (h5 == 0) {
                atomicAdd(&lbuf[b * DDIM + e2], lsum);
                atomicAdd(&gbuf[b * DDIM + e2], gsum);
            }
        }
    }
}

// --- kernel 3: out[d] = sum_b g[b,d] / l[b,d] --------------------------------
__global__ void finish_kernel(const float* __restrict__ lbuf,
                              const float* __restrict__ gbuf,
                              float* __restrict__ out) {
    int d = blockIdx.x * blockDim.x + threadIdx.x;   // 0..511
    float s = 0.f;
    #pragma unroll
    for (int b = 0; b < BATCH; ++b)
        s += gbuf[b * DDIM + d] / lbuf[b * DDIM + d];
    out[d] = s;
}

extern "C" void kernel_launch(void* const* d_in, const int* in_sizes, int n_in,
                              void* d_out, int out_size, void* d_ws, size_t ws_size,
                              hipStream_t stream) {
    const float* h  = (const float*)d_in[0];
    const float* W1 = (const float*)d_in[1];
    const float* b1 = (const float*)d_in[2];
    const float* W2 = (const float*)d_in[3];
    float* out = (float*)d_out;

    char* ws = (char*)d_ws;
    short* W1pk = (short*)ws;                             // 512 KB (packed)
    short* W2pk = (short*)(ws + 512 * 1024);              // 512 KB (packed)
    float* lbuf = (float*)(ws + 1024 * 1024);             // 64 KB
    float* gbuf = (float*)(ws + 1024 * 1024 + 64 * 1024); // 64 KB

    prep_kernel<<<128, 256, 0, stream>>>(W1, W2, W1pk, W2pk, lbuf, gbuf);
    main_kernel<<<(BATCH * TLEN) / (BM * NT), BLOCK, 0, stream>>>(h, W1pk, b1, W2pk, lbuf, gbuf);
    finish_kernel<<<2, 256, 0, stream>>>(lbuf, gbuf, out);
}

// Round 5
// 536.035 us; speedup vs baseline: 1.9955x; 1.9955x over previous
//
#include <hip/hip_runtime.h>
#include <math.h>

// Problem constants
#define BATCH 32
#define TLEN  4096
#define DDIM  512
#define BM    32      // rows per block (32 KB LDS -> 2 blocks/CU co-resident)
#define BLOCK 512     // 8 waves; wave w owns output cols [64w, 64w+64)
// r11: real TLP test. Budget closure: r9's 84k cyc/block = W-load L2 latency
// (~45k, 1-deep prefetch covers ~70 of ~300 cyc, only 2 waves/SIMD to hide)
// + stage 13k + VALU 22k + MFMA 8k. r8 proved 32KB LDS -> 2.6 blocks/CU but
// was spill-poisoned (VGPR forced to 40, 236MB scratch). Here: BM=32 halves
// accumulators so peak pressure ~95-115 regs; __launch_bounds__(512,4) caps
// at 128 -> 2 blocks/CU, 4 waves/SIMD, no spills. W L2 traffic doubles
// (16 MB/CU) -- bandwidth that overlaps, replacing latency that doesn't.
// Epilogue h comes from LDS (16 packed bf16 regs grabbed before u overwrite):
// no global reads after stage.

typedef __attribute__((ext_vector_type(8)))  short bf16x8;   // MFMA A/B frag
typedef __attribute__((ext_vector_type(16))) float f32x16;   // MFMA C/D frag (32x32)
typedef __attribute__((ext_vector_type(4)))  short s16x4;    // 8B LDS store

__device__ __forceinline__ short f32_to_bf16_rne(float f) {
    union { float f; unsigned int u; } v; v.f = f;
    unsigned int r = (v.u + 0x7FFFu + ((v.u >> 16) & 1u)) >> 16;
    return (short)r;
}
__device__ __forceinline__ float bf16_to_f32(unsigned int s) {
    union { unsigned int u; float f; } v;
    v.u = (s & 0xFFFFu) << 16;
    return v.f;
}
__device__ __forceinline__ float fast_tanh(float x) {
    x = fminf(fmaxf(x, -15.f), 15.f);
    float t = __expf(2.0f * x);
    return (t - 1.0f) / (t + 1.0f);
}

// XOR swizzle on 16B (8-short) granules. Measured 0 bank conflicts (r2-r9).
__device__ __forceinline__ int lds_idx(int r, int c) {
    int g = (c >> 3) ^ (r & 31);
    return r * DDIM + (g << 3) + (c & 7);
}

// --- kernel 1: W fp32 -> bf16 packed into MFMA-fragment order; zero l/g ------
// Element (e, d): E=e>>5, r=e&31, C=d>>4, half=(d>>3)&1, j=d&7
//   packed[ ((E*32 + C)*64 + half*32 + r)*8 + j ]
// Kernel-side (lane l): tile (E,C) base + l*8 supplies
//   W[E*32 + (l&31)][C*16 + 8*(l>>5) + j]  == MFMA fragment element.
__global__ void prep_kernel(const float* __restrict__ W1, const float* __restrict__ W2,
                            short* __restrict__ W1pk, short* __restrict__ W2pk,
                            float* __restrict__ lbuf, float* __restrict__ gbuf) {
    int i = blockIdx.x * blockDim.x + threadIdx.x;   // 0 .. 32767
    int e  = i >> 6;                 // source row
    int d0 = (i & 63) << 3;          // source col of this 8-run
    int E = e >> 5, r = e & 31, C = d0 >> 4, half = (d0 >> 3) & 1;
    size_t src = (size_t)e * DDIM + d0;
    size_t dst = ((size_t)(E * 32 + C) * 64 + half * 32 + r) * 8;
    bf16x8 p1, p2;
    #pragma unroll
    for (int j = 0; j < 8; ++j) {
        p1[j] = f32_to_bf16_rne(W1[src + j]);
        p2[j] = f32_to_bf16_rne(W2[src + j]);
    }
    *(bf16x8*)&W1pk[dst] = p1;
    *(bf16x8*)&W2pk[dst] = p2;
    if (i < BATCH * DDIM) { lbuf[i] = 0.f; gbuf[i] = 0.f; }
}

// --- kernel 2: fused u=tanh(hW1^T+b1); s=uW2^T; accumulate l,g ---------------
__global__ __launch_bounds__(BLOCK, 4)   // cap 128 VGPR -> 2 blocks/CU
void main_kernel(const float* __restrict__ h,
                 const short* __restrict__ W1pk,
                 const float* __restrict__ b1,
                 const short* __restrict__ W2pk,
                 float* __restrict__ lbuf, float* __restrict__ gbuf) {
    __shared__ __align__(16) short sh[BM * DDIM];   // 32 KB: h tile, then u tile

    const int tid  = threadIdx.x;
    const int row0 = blockIdx.x * BM;
    const int b    = row0 / TLEN;       // BM divides TLEN: no batch straddle

    // ---- stage: global fp32 h -> LDS bf16 (coalesced float4 loads) ----
    {
        const float4* hp = (const float4*)(h + (size_t)row0 * DDIM);
        #pragma unroll
        for (int i = 0; i < (BM * DDIM / 4) / BLOCK; ++i) {   // 8 iters
            int idx  = tid + i * BLOCK;          // float4 index
            float4 v = hp[idx];
            int flat = idx * 4;
            int r = flat >> 9;                   // /512
            int c = flat & (DDIM - 1);
            s16x4 p;
            p.x = f32_to_bf16_rne(v.x); p.y = f32_to_bf16_rne(v.y);
            p.z = f32_to_bf16_rne(v.z); p.w = f32_to_bf16_rne(v.w);
            *(s16x4*)&sh[lds_idx(r, c)] = p;
        }
    }
    __syncthreads();

    const int wave = tid >> 6;
    const int lane = tid & 63;
    const int l32  = lane & 31;
    const int h5   = lane >> 5;       // 0/1
    const int e0   = wave * 64;       // this wave's 64-col slice (both GEMMs)

    // ========== GEMM1 (swapped): C[e][t] = sum_d W1[e][d] * h[t][d] ==========
    // A-frag = W1 packed (coalesced: lane*16B), B-frag = h^T from LDS.
    f32x16 acc[2];                    // [eb]
    #pragma unroll
    for (int i = 0; i < 2; ++i)
        #pragma unroll
        for (int r = 0; r < 16; ++r) acc[i][r] = 0.f;

    const short* W1p = W1pk + (size_t)(e0 >> 5) * (32 * 512) + lane * 8;
    bf16x8 wc[2][2], wn[2][2];        // [eb][ksub], 1-iter prefetch
    #pragma unroll
    for (int eb = 0; eb < 2; ++eb)
        #pragma unroll
        for (int ks = 0; ks < 2; ++ks)
            wc[eb][ks] = *(const bf16x8*)(W1p + (eb * 32 + ks) * 512);

    for (int k0 = 0; k0 < DDIM; k0 += 32) {
        const int kb = k0 >> 4;
        bf16x8 hf[2];                 // [ksub]
        #pragma unroll
        for (int ks = 0; ks < 2; ++ks)
            hf[ks] = *(const bf16x8*)&sh[lds_idx(l32, k0 + ks * 16 + 8 * h5)];
        // prefetch next k-chunk (last iter overreads into adjacent ws: ok)
        #pragma unroll
        for (int eb = 0; eb < 2; ++eb)
            #pragma unroll
            for (int ks = 0; ks < 2; ++ks)
                wn[eb][ks] = *(const bf16x8*)(W1p + (eb * 32 + kb + 2 + ks) * 512);
        #pragma unroll
        for (int eb = 0; eb < 2; ++eb)
            #pragma unroll
            for (int ks = 0; ks < 2; ++ks)
                acc[eb] = __builtin_amdgcn_mfma_f32_32x32x16_bf16(
                    wc[eb][ks], hf[ks], acc[eb], 0, 0, 0);
        #pragma unroll
        for (int eb = 0; eb < 2; ++eb)
            #pragma unroll
            for (int ks = 0; ks < 2; ++ks) wc[eb][ks] = wn[eb][ks];
    }

    // issue GEMM2's first W2 frags: L2 latency hides under tanh+write+bars
    const short* W2p = W2pk + (size_t)(e0 >> 5) * (32 * 512) + lane * 8;
    bf16x8 w2c[2][2], w2n[2][2];      // [cb][ksub]
    #pragma unroll
    for (int cb = 0; cb < 2; ++cb)
        #pragma unroll
        for (int ks = 0; ks < 2; ++ks)
            w2c[cb][ks] = *(const bf16x8*)(W2p + (cb * 32 + ks) * 512);

    // bias + tanh. C/D map: col(t)=lane&31, row(e)=(r&3)+8*(r>>2)+4*h5 (+32*eb)
    #pragma unroll
    for (int eb = 0; eb < 2; ++eb) {
        float4 bv[4];
        #pragma unroll
        for (int q = 0; q < 4; ++q)
            bv[q] = *(const float4*)&b1[e0 + 32 * eb + 4 * h5 + 8 * q];
        #pragma unroll
        for (int r = 0; r < 16; ++r)
            acc[eb][r] = fast_tanh(acc[eb][r] + bv[r >> 2][r & 3]);
    }

    // grab this thread's epilogue h values from LDS before u overwrites it.
    // epilogue needs h[tt][e2], tt = 4*h5 + (r&3) + 8*(r>>2), r = 0..15,
    // for e2 = e0 + 32*cb + l32. Pack pairs (r=2q, 2q+1) -> rows tt0, tt0+1.
    unsigned int hpk[2][8];
    #pragma unroll
    for (int cb = 0; cb < 2; ++cb) {
        int e2 = e0 + 32 * cb + l32;
        #pragma unroll
        for (int q = 0; q < 8; ++q) {
            int tt0 = 4 * h5 + ((2 * q) & 3) + 8 * (q >> 1);
            unsigned int lo = (unsigned short)sh[lds_idx(tt0, e2)];
            unsigned int hi = (unsigned short)sh[lds_idx(tt0 + 1, e2)];
            hpk[cb][q] = lo | (hi << 16);
        }
    }

    __syncthreads();   // all waves done reading h tile; safe to overwrite with u

    // write u^T frags as u[t][e]: lane owns fixed t=l32, 4-consec-e runs -> b64
    #pragma unroll
    for (int eb = 0; eb < 2; ++eb) {
        #pragma unroll
        for (int q = 0; q < 4; ++q) {
            int e = e0 + 32 * eb + 4 * h5 + 8 * q;
            s16x4 p;
            p.x = f32_to_bf16_rne(acc[eb][4 * q + 0]);
            p.y = f32_to_bf16_rne(acc[eb][4 * q + 1]);
            p.z = f32_to_bf16_rne(acc[eb][4 * q + 2]);
            p.w = f32_to_bf16_rne(acc[eb][4 * q + 3]);
            *(s16x4*)&sh[lds_idx(l32, e)] = p;
        }
    }
    __syncthreads();

    // ========== GEMM2 (normal): s[t][e2] = sum_e u[t][e] * W2[e2][e] =========
    f32x16 acc2[2];                   // [cb]
    #pragma unroll
    for (int i = 0; i < 2; ++i)
        #pragma unroll
        for (int r = 0; r < 16; ++r) acc2[i][r] = 0.f;

    for (int k0 = 0; k0 < DDIM; k0 += 32) {
        const int kb = k0 >> 4;
        bf16x8 uf[2];                 // [ksub]
        #pragma unroll
        for (int ks = 0; ks < 2; ++ks)
            uf[ks] = *(const bf16x8*)&sh[lds_idx(l32, k0 + ks * 16 + 8 * h5)];
        #pragma unroll
        for (int cb = 0; cb < 2; ++cb)
            #pragma unroll
            for (int ks = 0; ks < 2; ++ks)
                w2n[cb][ks] = *(const bf16x8*)(W2p + (cb * 32 + kb + 2 + ks) * 512);
        #pragma unroll
        for (int cb = 0; cb < 2; ++cb)
            #pragma unroll
            for (int ks = 0; ks < 2; ++ks)
                acc2[cb] = __builtin_amdgcn_mfma_f32_32x32x16_bf16(
                    uf[ks], w2c[cb][ks], acc2[cb], 0, 0, 0);
        #pragma unroll
        for (int cb = 0; cb < 2; ++cb)
            #pragma unroll
            for (int ks = 0; ks < 2; ++ks) w2c[cb][ks] = w2n[cb][ks];
    }

    // epilogue: e = exp(s); l += e; g += e*h (h from packed LDS-grabbed regs).
    // lane holds 16 of 32 t's; partner (lane^32) holds the other 16.
    #pragma unroll
    for (int cb = 0; cb < 2; ++cb) {
        const int e2 = e0 + 32 * cb + l32;
        float lsum = 0.f, gsum = 0.f;
        #pragma unroll
        for (int r = 0; r < 16; ++r) {
            float hv = bf16_to_f32(hpk[cb][r >> 1] >> (16 * (r & 1)));
            float ev = __expf(acc2[cb][r]);       // |s| small: no max-sub
            lsum += ev;
            gsum += ev * hv;
        }
        lsum += __shfl_xor(lsum, 32);
        gsum += __shfl_xor(gsum, 32);
        if (h5 == 0) {
            atomicAdd(&lbuf[b * DDIM + e2], lsum);
            atomicAdd(&gbuf[b * DDIM + e2], gsum);
        }
    }
}

// --- kernel 3: out[d] = sum_b g[b,d] / l[b,d] --------------------------------
__global__ void finish_kernel(const float* __restrict__ lbuf,
                              const float* __restrict__ gbuf,
                              float* __restrict__ out) {
    int d = blockIdx.x * blockDim.x + threadIdx.x;   // 0..511
    float s = 0.f;
    #pragma unroll
    for (int b = 0; b < BATCH; ++b)
        s += gbuf[b * DDIM + d] / lbuf[b * DDIM + d];
    out[d] = s;
}

extern "C" void kernel_launch(void* const* d_in, const int* in_sizes, int n_in,
                              void* d_out, int out_size, void* d_ws, size_t ws_size,
                              hipStream_t stream) {
    const float* h  = (const float*)d_in[0];
    const float* W1 = (const float*)d_in[1];
    const float* b1 = (const float*)d_in[2];
    const float* W2 = (const float*)d_in[3];
    float* out = (float*)d_out;

    char* ws = (char*)d_ws;
    short* W1pk = (short*)ws;                             // 512 KB (packed)
    short* W2pk = (short*)(ws + 512 * 1024);              // 512 KB (packed)
    float* lbuf = (float*)(ws + 1024 * 1024);             // 64 KB
    float* gbuf = (float*)(ws + 1024 * 1024 + 64 * 1024); // 64 KB

    prep_kernel<<<128, 256, 0, stream>>>(W1, W2, W1pk, W2pk, lbuf, gbuf);
    main_kernel<<<(BATCH * TLEN) / BM, BLOCK, 0, stream>>>(h, W1pk, b1, W2pk, lbuf, gbuf);
    finish_kernel<<<2, 256, 0, stream>>>(lbuf, gbuf, out);
}